// Round 1
// baseline (7276.697 us; speedup 1.0000x reference)
//
#include <hip/hip_runtime.h>
#include <hip/hip_bf16.h>

// Problem constants
#define S_LEN  2048
#define DMODEL 2048
#define NH     32
#define NG     8
#define DK     64
#define DV     64

// -------------------------------------------------------------------------
// Generic tiled fp32 GEMM with bias: C[M,N] = A[M,K] @ B[K,N] + bias[N]
// 16x16 tiles, one thread per output element. All dims divisible by 16.
// -------------------------------------------------------------------------
__global__ void gemm_bias_f32(const float* __restrict__ A,
                              const float* __restrict__ B,
                              const float* __restrict__ bias,
                              float* __restrict__ C,
                              int M, int N, int K) {
    __shared__ float As[16][17];
    __shared__ float Bs[16][17];
    const int tx = threadIdx.x;           // 0..15 (N dir)
    const int ty = threadIdx.y;           // 0..15 (M dir)
    const int row = blockIdx.y * 16 + ty;
    const int col = blockIdx.x * 16 + tx;

    float acc = 0.0f;
    for (int k0 = 0; k0 < K; k0 += 16) {
        As[ty][tx] = A[row * K + (k0 + tx)];
        Bs[ty][tx] = B[(k0 + ty) * N + col];
        __syncthreads();
#pragma unroll
        for (int kk = 0; kk < 16; ++kk)
            acc += As[ty][kk] * Bs[kk][tx];
        __syncthreads();
    }
    C[row * N + col] = acc + bias[col];
}

// -------------------------------------------------------------------------
// Causal GQA attention, one wave (64 lanes) per (head, query row).
// lane = channel index in [0,64). Online softmax over keys j = 0..s.
// Q layout: [S, NH*DK] (col = h*64+d); K/V layout: [S, NG*64].
// Output A_out layout: [S, NH*DV] (col = h*64+d).
// -------------------------------------------------------------------------
__global__ void gqa_attention_f32(const float* __restrict__ Q,
                                  const float* __restrict__ K,
                                  const float* __restrict__ V,
                                  float* __restrict__ A_out) {
    const int s    = blockIdx.x;      // query row
    const int h    = blockIdx.y;      // head
    const int lane = threadIdx.x;     // 0..63
    const int g    = h >> 2;          // group head (repeat_interleave: h//4)

    // fold 1/sqrt(dk) into q
    const float qv = Q[s * (NH * DK) + h * DK + lane] * 0.125f;

    float m = -1e30f;   // running max
    float l = 0.0f;     // running denom
    float o = 0.0f;     // running numerator for this lane's channel

    const float* Kg = K + g * DK;
    const float* Vg = V + g * DV;

    for (int j = 0; j <= s; ++j) {
        float p = qv * Kg[j * (NG * DK) + lane];
        // full-wave butterfly sum -> all lanes hold the dot product
#pragma unroll
        for (int off = 32; off >= 1; off >>= 1)
            p += __shfl_xor(p, off, 64);

        const float mnew  = fmaxf(m, p);
        const float alpha = __expf(m - mnew);
        const float e     = __expf(p - mnew);
        l = l * alpha + e;
        o = o * alpha + e * Vg[j * (NG * DV) + lane];
        m = mnew;
    }

    A_out[s * (NH * DV) + h * DV + lane] = o / l;
}

// -------------------------------------------------------------------------
extern "C" void kernel_launch(void* const* d_in, const int* in_sizes, int n_in,
                              void* d_out, int out_size, void* d_ws, size_t ws_size,
                              hipStream_t stream) {
    const float* queries = (const float*)d_in[0];   // [1,2048,2048]
    const float* keys    = (const float*)d_in[1];
    const float* values  = (const float*)d_in[2];
    const float* Wq      = (const float*)d_in[3];   // [2048, 2048]
    const float* bq      = (const float*)d_in[4];
    const float* Wk      = (const float*)d_in[5];   // [2048, 512]
    const float* bk      = (const float*)d_in[6];
    const float* Wv      = (const float*)d_in[7];   // [2048, 512]
    const float* bv      = (const float*)d_in[8];
    const float* Wo      = (const float*)d_in[9];   // [2048, 2048]
    const float* bo      = (const float*)d_in[10];
    float* out = (float*)d_out;                     // [2048, 2048]

    // workspace layout (fp32): Q | K | V | attn_out
    float* Qp = (float*)d_ws;                       // 2048*2048
    float* Kp = Qp + (size_t)S_LEN * (NH * DK);     // 2048*512
    float* Vp = Kp + (size_t)S_LEN * (NG * DK);     // 2048*512
    float* Ap = Vp + (size_t)S_LEN * (NG * DV);     // 2048*2048

    dim3 blk(16, 16);

    // Q = queries @ Wq + bq   [2048, 2048]
    gemm_bias_f32<<<dim3((NH * DK) / 16, S_LEN / 16), blk, 0, stream>>>(
        queries, Wq, bq, Qp, S_LEN, NH * DK, DMODEL);
    // K = keys @ Wk + bk      [2048, 512]
    gemm_bias_f32<<<dim3((NG * DK) / 16, S_LEN / 16), blk, 0, stream>>>(
        keys, Wk, bk, Kp, S_LEN, NG * DK, DMODEL);
    // V = values @ Wv + bv    [2048, 512]
    gemm_bias_f32<<<dim3((NG * DV) / 16, S_LEN / 16), blk, 0, stream>>>(
        values, Wv, bv, Vp, S_LEN, NG * DV, DMODEL);

    // attention: one wave per (row, head)
    gqa_attention_f32<<<dim3(S_LEN, NH), dim3(64), 0, stream>>>(Qp, Kp, Vp, Ap);

    // out = A @ Wo + bo       [2048, 2048]
    gemm_bias_f32<<<dim3(DMODEL / 16, S_LEN / 16), blk, 0, stream>>>(
        Ap, Wo, bo, out, S_LEN, DMODEL, DMODEL);
}

// Round 2
// 3230.871 us; speedup vs baseline: 2.2522x; 2.2522x over previous
//
#include <hip/hip_runtime.h>
#include <hip/hip_bf16.h>

// Problem constants
#define S_LEN  2048
#define DMODEL 2048
#define NH     32
#define NG     8
#define DK     64
#define DV     64

// -------------------------------------------------------------------------
// Tiled fp32 GEMM with bias: C[M,N] = A[M,K] @ B[K,N] + bias[N]
// 64x64 block tile, BK=16, 256 threads, 4x4 outputs per thread.
// LDS stored k-major with +4 pad so b128 reads stay 16B-aligned.
// M,N divisible by 64; K divisible by 16.
// -------------------------------------------------------------------------
#define BM 64
#define BN 64
#define BK 16

__global__ __launch_bounds__(256) void gemm_bias_f32_v2(
        const float* __restrict__ A, const float* __restrict__ B,
        const float* __restrict__ bias, float* __restrict__ C,
        int M, int N, int K) {
    __shared__ float As[BK][BM + 4];   // [k][m]
    __shared__ float Bs[BK][BN + 4];   // [k][n]

    const int tx  = threadIdx.x;       // 0..15 -> n direction
    const int ty  = threadIdx.y;       // 0..15 -> m direction
    const int tid = ty * 16 + tx;
    const int row0 = blockIdx.y * BM;
    const int col0 = blockIdx.x * BN;

    float acc[4][4] = {};

    const int a_k = tid % 16;          // k index for A load
    const int a_m = tid / 16;          // base m (0..15), step 16
    const int b_n = tid % 64;          // n index for B load
    const int b_k = tid / 64;          // base k (0..3), step 4

    for (int k0 = 0; k0 < K; k0 += BK) {
#pragma unroll
        for (int i = 0; i < 4; ++i)
            As[a_k][a_m + 16 * i] = A[(size_t)(row0 + a_m + 16 * i) * K + k0 + a_k];
#pragma unroll
        for (int i = 0; i < 4; ++i)
            Bs[b_k + 4 * i][b_n] = B[(size_t)(k0 + b_k + 4 * i) * N + col0 + b_n];
        __syncthreads();

#pragma unroll
        for (int kk = 0; kk < BK; ++kk) {
            const float4 a4 = *(const float4*)&As[kk][ty * 4];
            const float4 b4 = *(const float4*)&Bs[kk][tx * 4];
            const float a[4] = {a4.x, a4.y, a4.z, a4.w};
            const float b[4] = {b4.x, b4.y, b4.z, b4.w};
#pragma unroll
            for (int i = 0; i < 4; ++i)
#pragma unroll
                for (int j = 0; j < 4; ++j)
                    acc[i][j] = fmaf(a[i], b[j], acc[i][j]);
        }
        __syncthreads();
    }

    const float4 bias4 = *(const float4*)&bias[col0 + tx * 4];
#pragma unroll
    for (int i = 0; i < 4; ++i) {
        float4 r;
        r.x = acc[i][0] + bias4.x;
        r.y = acc[i][1] + bias4.y;
        r.z = acc[i][2] + bias4.z;
        r.w = acc[i][3] + bias4.w;
        *(float4*)&C[(size_t)(row0 + ty * 4 + i) * N + col0 + tx * 4] = r;
    }
}

// -------------------------------------------------------------------------
// Causal GQA attention, LDS-tiled.
// Block = 128 threads handling 128 consecutive q rows for one head.
// Thread owns one q row: q[64] and o[64] live in registers.
// K/V staged in LDS as 64-key tiles; compute reads are wave-broadcast
// float4 (all lanes read the same address -> conflict-free).
// -------------------------------------------------------------------------
#define QROWS 128
#define JTILE 64

__global__ __launch_bounds__(128) void gqa_attn_tiled(
        const float* __restrict__ Q, const float* __restrict__ K,
        const float* __restrict__ V, float* __restrict__ A_out) {
    __shared__ float4 Ks4[JTILE * 16];   // [jj][d4]
    __shared__ float4 Vs4[JTILE * 16];

    const int qt  = blockIdx.x;          // q-tile (128 rows)
    const int h   = blockIdx.y;          // head
    const int g   = h >> 2;              // group head (repeat_interleave h//4)
    const int tid = threadIdx.x;         // 0..127
    const int r   = qt * QROWS + tid;    // this thread's q row

    // load q row into registers, fold in 1/sqrt(dk)
    float4 q4[16];
    const float4* qrow = (const float4*)&Q[(size_t)r * (NH * DK) + h * DK];
#pragma unroll
    for (int d4 = 0; d4 < 16; ++d4) {
        float4 t = qrow[d4];
        t.x *= 0.125f; t.y *= 0.125f; t.z *= 0.125f; t.w *= 0.125f;
        q4[d4] = t;
    }

    float m = -1e30f, l = 0.0f;
    float4 o4[16];
#pragma unroll
    for (int d4 = 0; d4 < 16; ++d4) o4[d4] = make_float4(0.f, 0.f, 0.f, 0.f);

    const int jt_max = 2 * qt + 1;       // tiles of 64 keys covering rows < (qt+1)*128

    for (int jt = 0; jt <= jt_max; ++jt) {
        // cooperative tile load: 64 rows x 16 float4 each, 1024 float4 / 128 thr
        const int j0 = jt * JTILE;
#pragma unroll
        for (int i = 0; i < 8; ++i) {
            const int flat = i * 128 + tid;          // 0..1023
            const int jr = flat / 16, c4 = flat % 16;
            Ks4[jr * 16 + c4] = *(const float4*)&K[(size_t)(j0 + jr) * (NG * DK) + g * DK + c4 * 4];
            Vs4[jr * 16 + c4] = *(const float4*)&V[(size_t)(j0 + jr) * (NG * DV) + g * DV + c4 * 4];
        }
        __syncthreads();

        const int jmax = min(JTILE - 1, r - j0);     // causal bound (may be <0)
        for (int jj = 0; jj <= jmax; ++jj) {
            // score = q . k_jj  (broadcast LDS reads)
            float4 s4 = make_float4(0.f, 0.f, 0.f, 0.f);
#pragma unroll
            for (int d4 = 0; d4 < 16; ++d4) {
                const float4 kv = Ks4[jj * 16 + d4];
                s4.x = fmaf(q4[d4].x, kv.x, s4.x);
                s4.y = fmaf(q4[d4].y, kv.y, s4.y);
                s4.z = fmaf(q4[d4].z, kv.z, s4.z);
                s4.w = fmaf(q4[d4].w, kv.w, s4.w);
            }
            const float p = (s4.x + s4.y) + (s4.z + s4.w);

            const float mnew  = fmaxf(m, p);
            const float alpha = __expf(m - mnew);
            const float e     = __expf(p - mnew);
            l = l * alpha + e;
            m = mnew;
#pragma unroll
            for (int d4 = 0; d4 < 16; ++d4) {
                const float4 vv = Vs4[jj * 16 + d4];
                o4[d4].x = fmaf(o4[d4].x, alpha, e * vv.x);
                o4[d4].y = fmaf(o4[d4].y, alpha, e * vv.y);
                o4[d4].z = fmaf(o4[d4].z, alpha, e * vv.z);
                o4[d4].w = fmaf(o4[d4].w, alpha, e * vv.w);
            }
        }
        __syncthreads();
    }

    const float inv_l = 1.0f / l;
    float4* orow = (float4*)&A_out[(size_t)r * (NH * DV) + h * DV];
#pragma unroll
    for (int d4 = 0; d4 < 16; ++d4) {
        float4 t = o4[d4];
        t.x *= inv_l; t.y *= inv_l; t.z *= inv_l; t.w *= inv_l;
        orow[d4] = t;
    }
}

// -------------------------------------------------------------------------
extern "C" void kernel_launch(void* const* d_in, const int* in_sizes, int n_in,
                              void* d_out, int out_size, void* d_ws, size_t ws_size,
                              hipStream_t stream) {
    const float* queries = (const float*)d_in[0];
    const float* keys    = (const float*)d_in[1];
    const float* values  = (const float*)d_in[2];
    const float* Wq      = (const float*)d_in[3];
    const float* bq      = (const float*)d_in[4];
    const float* Wk      = (const float*)d_in[5];
    const float* bk      = (const float*)d_in[6];
    const float* Wv      = (const float*)d_in[7];
    const float* bv      = (const float*)d_in[8];
    const float* Wo      = (const float*)d_in[9];
    const float* bo      = (const float*)d_in[10];
    float* out = (float*)d_out;

    float* Qp = (float*)d_ws;                       // 2048*2048
    float* Kp = Qp + (size_t)S_LEN * (NH * DK);     // 2048*512
    float* Vp = Kp + (size_t)S_LEN * (NG * DK);     // 2048*512
    float* Ap = Vp + (size_t)S_LEN * (NG * DV);     // 2048*2048

    dim3 blk(16, 16);

    gemm_bias_f32_v2<<<dim3((NH * DK) / BN, S_LEN / BM), blk, 0, stream>>>(
        queries, Wq, bq, Qp, S_LEN, NH * DK, DMODEL);
    gemm_bias_f32_v2<<<dim3((NG * DK) / BN, S_LEN / BM), blk, 0, stream>>>(
        keys, Wk, bk, Kp, S_LEN, NG * DK, DMODEL);
    gemm_bias_f32_v2<<<dim3((NG * DV) / BN, S_LEN / BM), blk, 0, stream>>>(
        values, Wv, bv, Vp, S_LEN, NG * DV, DMODEL);

    gqa_attn_tiled<<<dim3(S_LEN / QROWS, NH), dim3(128), 0, stream>>>(Qp, Kp, Vp, Ap);

    gemm_bias_f32_v2<<<dim3(DMODEL / BN, S_LEN / BM), blk, 0, stream>>>(
        Ap, Wo, bo, out, S_LEN, DMODEL, DMODEL);
}

// Round 3
// 1259.416 us; speedup vs baseline: 5.7778x; 2.5654x over previous
//
#include <hip/hip_runtime.h>
#include <hip/hip_bf16.h>

#define S_LEN  2048
#define DMODEL 2048
#define NH     32
#define NG     8
#define DK     64
#define DV     64

typedef short bf16x8 __attribute__((ext_vector_type(8)));
typedef float f32x4  __attribute__((ext_vector_type(4)));

__device__ __forceinline__ ushort f32_to_bf16(float f) {
    uint u = __float_as_uint(f);
    return (ushort)((u + 0x7fffu + ((u >> 16) & 1u)) >> 16);   // RNE
}
__device__ __forceinline__ float bf16_to_f32(ushort h) {
    return __uint_as_float(((uint)h) << 16);
}
__device__ __forceinline__ void unpack8(uint4 u, float* f) {
    f[0] = bf16_to_f32((ushort)(u.x & 0xffffu)); f[1] = bf16_to_f32((ushort)(u.x >> 16));
    f[2] = bf16_to_f32((ushort)(u.y & 0xffffu)); f[3] = bf16_to_f32((ushort)(u.y >> 16));
    f[4] = bf16_to_f32((ushort)(u.z & 0xffffu)); f[5] = bf16_to_f32((ushort)(u.z >> 16));
    f[6] = bf16_to_f32((ushort)(u.w & 0xffffu)); f[7] = bf16_to_f32((ushort)(u.w >> 16));
}

// ---------------------------------------------------------------- cast f32->bf16
__global__ void cast_f32_to_bf16(const float* __restrict__ in,
                                 ushort* __restrict__ out, int n8) {
    int i = blockIdx.x * blockDim.x + threadIdx.x;
    const int stride = gridDim.x * blockDim.x;
    for (; i < n8; i += stride) {
        const float4 a = ((const float4*)in)[2 * i];
        const float4 b = ((const float4*)in)[2 * i + 1];
        uint4 o;
        o.x = (uint)f32_to_bf16(a.x) | ((uint)f32_to_bf16(a.y) << 16);
        o.y = (uint)f32_to_bf16(a.z) | ((uint)f32_to_bf16(a.w) << 16);
        o.z = (uint)f32_to_bf16(b.x) | ((uint)f32_to_bf16(b.y) << 16);
        o.w = (uint)f32_to_bf16(b.z) | ((uint)f32_to_bf16(b.w) << 16);
        ((uint4*)out)[i] = o;
    }
}

// ------------------------------------------------- W[K][N] f32 -> Wt[N][K] bf16
__global__ void transpose_cast_bf16(const float* __restrict__ W,
                                    ushort* __restrict__ Wt, int K, int N) {
    __shared__ float t[32][33];
    const int n0 = blockIdx.x * 32, k0 = blockIdx.y * 32;
    const int tx = threadIdx.x, ty = threadIdx.y;   // 32 x 8
#pragma unroll
    for (int i = 0; i < 4; ++i)
        t[ty + 8 * i][tx] = W[(size_t)(k0 + ty + 8 * i) * N + n0 + tx];
    __syncthreads();
#pragma unroll
    for (int i = 0; i < 4; ++i)
        Wt[(size_t)(n0 + ty + 8 * i) * K + k0 + tx] = f32_to_bf16(t[tx][ty + 8 * i]);
}

// ------------------------------------------------------------- bf16 MFMA GEMM
// C[M][N] = A[M][K] @ Bt[N][K]^T + bias.  128x128 tile, 4 waves (2x2 of 64x64),
// each wave 4x4 frags of mfma_f32_16x16x32_bf16. LDS row stride 40 bf16 (2-way
// bank aliasing only). OUT_F32 selects f32 vs bf16 C.
template <bool OUT_F32>
__global__ __launch_bounds__(256) void gemm_bf16_mfma(
        const ushort* __restrict__ A, const ushort* __restrict__ Bt,
        const float* __restrict__ bias, void* __restrict__ Cv,
        int M, int N, int K) {
    __shared__ ushort As[128 * 40];
    __shared__ ushort Bs[128 * 40];
    const int tid  = threadIdx.x;
    const int lane = tid & 63, wave = tid >> 6;
    const int wm = wave & 1, wn = wave >> 1;
    const int l15 = lane & 15, quad = lane >> 4;
    const int row0 = blockIdx.y * 128, col0 = blockIdx.x * 128;

    f32x4 acc[4][4];
#pragma unroll
    for (int i = 0; i < 4; ++i)
#pragma unroll
        for (int j = 0; j < 4; ++j) {
            f32x4 z = {0.f, 0.f, 0.f, 0.f};
            acc[i][j] = z;
        }

    const int c1 = tid, c2 = tid + 256;
    const int r1 = c1 >> 2, k1o = (c1 & 3) * 8;
    const int r2 = c2 >> 2, k2o = (c2 & 3) * 8;

    for (int k0 = 0; k0 < K; k0 += 32) {
        const bf16x8 a1 = *(const bf16x8*)&A [(size_t)(row0 + r1) * K + k0 + k1o];
        const bf16x8 a2 = *(const bf16x8*)&A [(size_t)(row0 + r2) * K + k0 + k2o];
        const bf16x8 b1 = *(const bf16x8*)&Bt[(size_t)(col0 + r1) * K + k0 + k1o];
        const bf16x8 b2 = *(const bf16x8*)&Bt[(size_t)(col0 + r2) * K + k0 + k2o];
        __syncthreads();
        *(bf16x8*)&As[r1 * 40 + k1o] = a1;
        *(bf16x8*)&As[r2 * 40 + k2o] = a2;
        *(bf16x8*)&Bs[r1 * 40 + k1o] = b1;
        *(bf16x8*)&Bs[r2 * 40 + k2o] = b2;
        __syncthreads();

        bf16x8 af[4], bf[4];
#pragma unroll
        for (int mi = 0; mi < 4; ++mi)
            af[mi] = *(const bf16x8*)&As[(wm * 64 + mi * 16 + l15) * 40 + quad * 8];
#pragma unroll
        for (int ni = 0; ni < 4; ++ni)
            bf[ni] = *(const bf16x8*)&Bs[(wn * 64 + ni * 16 + l15) * 40 + quad * 8];
#pragma unroll
        for (int mi = 0; mi < 4; ++mi)
#pragma unroll
            for (int ni = 0; ni < 4; ++ni)
                acc[mi][ni] = __builtin_amdgcn_mfma_f32_16x16x32_bf16(
                    af[mi], bf[ni], acc[mi][ni], 0, 0, 0);
    }

    // epilogue: D row = quad*4+reg, col = l15
#pragma unroll
    for (int mi = 0; mi < 4; ++mi)
#pragma unroll
        for (int ni = 0; ni < 4; ++ni) {
            const int col = col0 + wn * 64 + ni * 16 + l15;
            const float bv = bias[col];
#pragma unroll
            for (int reg = 0; reg < 4; ++reg) {
                const int row = row0 + wm * 64 + mi * 16 + quad * 4 + reg;
                const float val = acc[mi][ni][reg] + bv;
                if (OUT_F32)
                    ((float*)Cv)[(size_t)row * N + col] = val;
                else
                    ((ushort*)Cv)[(size_t)row * N + col] = f32_to_bf16(val);
            }
        }
}

// ------------------------------------------------------------- attention v2
// 256 threads = 4 waves; wave w owns rows qt*64 + w*16 .. +15; within a wave
// lane = (dimq<<4)|rowlocal: 4 threads per q-row, each owns 16 dims.
// K/V staged as 64-key f32 LDS tiles. Online softmax, 2-key unrolled.
__global__ __launch_bounds__(256) void gqa_attn_v2(
        const ushort* __restrict__ Qb, const ushort* __restrict__ Kb,
        const ushort* __restrict__ Vb, ushort* __restrict__ Ab) {
    __shared__ float Ks[64 * 64];
    __shared__ float Vs[64 * 64];

    const int qt   = (int)(gridDim.x - 1 - blockIdx.x);   // heavy tiles first
    const int h    = blockIdx.y, g = h >> 2;
    const int tid  = threadIdx.x;
    const int lane = tid & 63, wave = tid >> 6;
    const int l15  = lane & 15, dimq = lane >> 4;
    const int r    = qt * 64 + wave * 16 + l15;

    // q: this thread's 16 dims, scale folded
    float q[16];
    {
        const size_t base = (size_t)r * (NH * DK) + h * DK + dimq * 16;
        float tmp[8];
        unpack8(*(const uint4*)&Qb[base], tmp);
#pragma unroll
        for (int i = 0; i < 8; ++i) q[i] = tmp[i] * 0.125f;
        unpack8(*(const uint4*)&Qb[base + 8], tmp);
#pragma unroll
        for (int i = 0; i < 8; ++i) q[8 + i] = tmp[i] * 0.125f;
    }

    float4 o4[4];
#pragma unroll
    for (int i = 0; i < 4; ++i) o4[i] = make_float4(0.f, 0.f, 0.f, 0.f);
    float m = -1e30f, l = 0.f;

    for (int jt = 0; jt <= qt; ++jt) {
        const int j0 = jt * 64;
        // stage 64 keys x 64 dims of K and V (bf16 global -> f32 LDS)
#pragma unroll
        for (int c = tid; c < 512; c += 256) {
            const int row = c >> 3, c8 = c & 7;
            float kf[8], vf[8];
            unpack8(*(const uint4*)&Kb[(size_t)(j0 + row) * (NG * DK) + g * DK + c8 * 8], kf);
            unpack8(*(const uint4*)&Vb[(size_t)(j0 + row) * (NG * DV) + g * DV + c8 * 8], vf);
            *(float4*)&Ks[row * 64 + c8 * 8]     = make_float4(kf[0], kf[1], kf[2], kf[3]);
            *(float4*)&Ks[row * 64 + c8 * 8 + 4] = make_float4(kf[4], kf[5], kf[6], kf[7]);
            *(float4*)&Vs[row * 64 + c8 * 8]     = make_float4(vf[0], vf[1], vf[2], vf[3]);
            *(float4*)&Vs[row * 64 + c8 * 8 + 4] = make_float4(vf[4], vf[5], vf[6], vf[7]);
        }
        __syncthreads();

        const int jmax = min(63, r - j0);

        auto score = [&](int jj) -> float {
            const float* kb = &Ks[jj * 64 + dimq * 16];
            const float4 k0 = *(const float4*)(kb);
            const float4 k1 = *(const float4*)(kb + 4);
            const float4 k2 = *(const float4*)(kb + 8);
            const float4 k3 = *(const float4*)(kb + 12);
            float pa = fmaf(q[0], k0.x, fmaf(q[4], k1.x, fmaf(q[8],  k2.x, q[12] * k3.x)));
            float pb = fmaf(q[1], k0.y, fmaf(q[5], k1.y, fmaf(q[9],  k2.y, q[13] * k3.y)));
            float pc = fmaf(q[2], k0.z, fmaf(q[6], k1.z, fmaf(q[10], k2.z, q[14] * k3.z)));
            float pd = fmaf(q[3], k0.w, fmaf(q[7], k1.w, fmaf(q[11], k2.w, q[15] * k3.w)));
            float p = (pa + pb) + (pc + pd);
            p += __shfl_xor(p, 16, 64);
            p += __shfl_xor(p, 32, 64);
            return p;
        };

        int jj = 0;
        for (; jj + 1 <= jmax; jj += 2) {
            const float p1 = score(jj);
            const float p2 = score(jj + 1);
            const float mnew = fmaxf(m, fmaxf(p1, p2));
            const float al = __expf(m - mnew);
            const float e1 = __expf(p1 - mnew);
            const float e2 = __expf(p2 - mnew);
            l = fmaf(l, al, e1 + e2);
            m = mnew;
            const float4* v1 = (const float4*)&Vs[jj * 64 + dimq * 16];
            const float4* v2 = (const float4*)&Vs[(jj + 1) * 64 + dimq * 16];
#pragma unroll
            for (int i = 0; i < 4; ++i) {
                const float4 a = v1[i], b = v2[i];
                o4[i].x = fmaf(o4[i].x, al, fmaf(e1, a.x, e2 * b.x));
                o4[i].y = fmaf(o4[i].y, al, fmaf(e1, a.y, e2 * b.y));
                o4[i].z = fmaf(o4[i].z, al, fmaf(e1, a.z, e2 * b.z));
                o4[i].w = fmaf(o4[i].w, al, fmaf(e1, a.w, e2 * b.w));
            }
        }
        if (jj <= jmax) {
            const float p1 = score(jj);
            const float mnew = fmaxf(m, p1);
            const float al = __expf(m - mnew);
            const float e1 = __expf(p1 - mnew);
            l = fmaf(l, al, e1);
            m = mnew;
            const float4* v1 = (const float4*)&Vs[jj * 64 + dimq * 16];
#pragma unroll
            for (int i = 0; i < 4; ++i) {
                const float4 a = v1[i];
                o4[i].x = fmaf(o4[i].x, al, e1 * a.x);
                o4[i].y = fmaf(o4[i].y, al, e1 * a.y);
                o4[i].z = fmaf(o4[i].z, al, e1 * a.z);
                o4[i].w = fmaf(o4[i].w, al, e1 * a.w);
            }
        }
        __syncthreads();
    }

    const float inv = 1.0f / l;
    float of[16];
#pragma unroll
    for (int i = 0; i < 4; ++i) {
        of[4 * i]     = o4[i].x * inv;
        of[4 * i + 1] = o4[i].y * inv;
        of[4 * i + 2] = o4[i].z * inv;
        of[4 * i + 3] = o4[i].w * inv;
    }
    uint4 p1, p2;
    p1.x = (uint)f32_to_bf16(of[0])  | ((uint)f32_to_bf16(of[1])  << 16);
    p1.y = (uint)f32_to_bf16(of[2])  | ((uint)f32_to_bf16(of[3])  << 16);
    p1.z = (uint)f32_to_bf16(of[4])  | ((uint)f32_to_bf16(of[5])  << 16);
    p1.w = (uint)f32_to_bf16(of[6])  | ((uint)f32_to_bf16(of[7])  << 16);
    p2.x = (uint)f32_to_bf16(of[8])  | ((uint)f32_to_bf16(of[9])  << 16);
    p2.y = (uint)f32_to_bf16(of[10]) | ((uint)f32_to_bf16(of[11]) << 16);
    p2.z = (uint)f32_to_bf16(of[12]) | ((uint)f32_to_bf16(of[13]) << 16);
    p2.w = (uint)f32_to_bf16(of[14]) | ((uint)f32_to_bf16(of[15]) << 16);
    const size_t ob = (size_t)r * (NH * DV) + h * DV + dimq * 16;
    *(uint4*)&Ab[ob]     = p1;
    *(uint4*)&Ab[ob + 8] = p2;
}

// ---------------------------------------------------------------------------
extern "C" void kernel_launch(void* const* d_in, const int* in_sizes, int n_in,
                              void* d_out, int out_size, void* d_ws, size_t ws_size,
                              hipStream_t stream) {
    const float* queries = (const float*)d_in[0];
    const float* keys    = (const float*)d_in[1];
    const float* values  = (const float*)d_in[2];
    const float* Wq      = (const float*)d_in[3];
    const float* bq      = (const float*)d_in[4];
    const float* Wk      = (const float*)d_in[5];
    const float* bk      = (const float*)d_in[6];
    const float* Wv      = (const float*)d_in[7];
    const float* bv      = (const float*)d_in[8];
    const float* Wo      = (const float*)d_in[9];
    const float* bo      = (const float*)d_in[10];
    float* out = (float*)d_out;

    const size_t MB = 1024 * 1024;
    unsigned char* w = (unsigned char*)d_ws;
    ushort* Xq  = (ushort*)(w + 0 * MB);    // [2048][2048] bf16
    ushort* Xk  = (ushort*)(w + 8 * MB);
    ushort* Xv  = (ushort*)(w + 16 * MB);
    ushort* Wqt = (ushort*)(w + 24 * MB);   // [2048][2048]
    ushort* Wkt = (ushort*)(w + 32 * MB);   // [512][2048]
    ushort* Wvt = (ushort*)(w + 34 * MB);
    ushort* Wot = (ushort*)(w + 36 * MB);   // [2048][2048]
    ushort* Qb  = (ushort*)(w + 44 * MB);   // [2048][2048]
    ushort* Kb  = (ushort*)(w + 52 * MB);   // [2048][512]
    ushort* Vb  = (ushort*)(w + 54 * MB);
    ushort* Ab  = (ushort*)(w + 56 * MB);   // [2048][2048]

    const int n8 = (S_LEN * DMODEL) / 8;
    cast_f32_to_bf16<<<1024, 256, 0, stream>>>(queries, Xq, n8);
    cast_f32_to_bf16<<<1024, 256, 0, stream>>>(keys,    Xk, n8);
    cast_f32_to_bf16<<<1024, 256, 0, stream>>>(values,  Xv, n8);

    dim3 tb(32, 8);
    transpose_cast_bf16<<<dim3(2048 / 32, 2048 / 32), tb, 0, stream>>>(Wq, Wqt, DMODEL, 2048);
    transpose_cast_bf16<<<dim3(512 / 32,  2048 / 32), tb, 0, stream>>>(Wk, Wkt, DMODEL, 512);
    transpose_cast_bf16<<<dim3(512 / 32,  2048 / 32), tb, 0, stream>>>(Wv, Wvt, DMODEL, 512);
    transpose_cast_bf16<<<dim3(2048 / 32, 2048 / 32), tb, 0, stream>>>(Wo, Wot, DMODEL, 2048);

    gemm_bf16_mfma<false><<<dim3(2048 / 128, 2048 / 128), 256, 0, stream>>>(
        Xq, Wqt, bq, Qb, S_LEN, 2048, DMODEL);
    gemm_bf16_mfma<false><<<dim3(512 / 128, 2048 / 128), 256, 0, stream>>>(
        Xk, Wkt, bk, Kb, S_LEN, 512, DMODEL);
    gemm_bf16_mfma<false><<<dim3(512 / 128, 2048 / 128), 256, 0, stream>>>(
        Xv, Wvt, bv, Vb, S_LEN, 512, DMODEL);

    gqa_attn_v2<<<dim3(32, 32), 256, 0, stream>>>(Qb, Kb, Vb, Ab);

    gemm_bf16_mfma<true><<<dim3(2048 / 128, 2048 / 128), 256, 0, stream>>>(
        Ab, Wot, bo, out, S_LEN, DMODEL, DMODEL);
}

// Round 5
// 472.708 us; speedup vs baseline: 15.3937x; 2.6643x over previous
//
#include <hip/hip_runtime.h>
#include <hip/hip_bf16.h>

#define S_LEN  2048
#define DMODEL 2048
#define NH     32
#define NG     8
#define DK     64
#define DV     64

typedef short bf16x8 __attribute__((ext_vector_type(8)));
typedef float f32x4  __attribute__((ext_vector_type(4)));

__device__ __forceinline__ ushort f32_to_bf16(float f) {
    uint u = __float_as_uint(f);
    return (ushort)((u + 0x7fffu + ((u >> 16) & 1u)) >> 16);   // RNE
}
__device__ __forceinline__ float bf16_to_f32(ushort h) {
    return __uint_as_float(((uint)h) << 16);
}

// ---------------------------------------------------------------- cast f32->bf16
__global__ void cast_f32_to_bf16(const float* __restrict__ in,
                                 ushort* __restrict__ out, int n8) {
    int i = blockIdx.x * blockDim.x + threadIdx.x;
    const int stride = gridDim.x * blockDim.x;
    for (; i < n8; i += stride) {
        const float4 a = ((const float4*)in)[2 * i];
        const float4 b = ((const float4*)in)[2 * i + 1];
        uint4 o;
        o.x = (uint)f32_to_bf16(a.x) | ((uint)f32_to_bf16(a.y) << 16);
        o.y = (uint)f32_to_bf16(a.z) | ((uint)f32_to_bf16(a.w) << 16);
        o.z = (uint)f32_to_bf16(b.x) | ((uint)f32_to_bf16(b.y) << 16);
        o.w = (uint)f32_to_bf16(b.z) | ((uint)f32_to_bf16(b.w) << 16);
        ((uint4*)out)[i] = o;
    }
}

// ------------------------------------------------- W[K][N] f32 -> Wt[N][K] bf16
__global__ void transpose_cast_bf16(const float* __restrict__ W,
                                    ushort* __restrict__ Wt, int K, int N) {
    __shared__ float t[32][33];
    const int n0 = blockIdx.x * 32, k0 = blockIdx.y * 32;
    const int tx = threadIdx.x, ty = threadIdx.y;   // 32 x 8
#pragma unroll
    for (int i = 0; i < 4; ++i)
        t[ty + 8 * i][tx] = W[(size_t)(k0 + ty + 8 * i) * N + n0 + tx];
    __syncthreads();
#pragma unroll
    for (int i = 0; i < 4; ++i)
        Wt[(size_t)(n0 + ty + 8 * i) * K + k0 + tx] = f32_to_bf16(t[tx][ty + 8 * i]);
}

// --------------------------------------------- bf16 [R][C] -> [C][R] transpose
__global__ void transpose_bf16(const ushort* __restrict__ in,
                               ushort* __restrict__ out, int R, int C) {
    __shared__ ushort t[32][34];
    const int c0 = blockIdx.x * 32, r0 = blockIdx.y * 32;
    const int tx = threadIdx.x, ty = threadIdx.y;   // 32 x 8
#pragma unroll
    for (int i = 0; i < 4; ++i)
        t[ty + 8 * i][tx] = in[(size_t)(r0 + ty + 8 * i) * C + c0 + tx];
    __syncthreads();
#pragma unroll
    for (int i = 0; i < 4; ++i)
        out[(size_t)(c0 + ty + 8 * i) * R + r0 + tx] = t[tx][ty + 8 * i];
}

// ------------------------------------------------------------- bf16 MFMA GEMM
// C[M][N] = A[M][K] @ Bt[N][K]^T + bias.  128x128 tile, 4 waves (2x2 of 64x64),
// each wave 4x4 frags of mfma_f32_16x16x32_bf16.
template <bool OUT_F32>
__global__ __launch_bounds__(256) void gemm_bf16_mfma(
        const ushort* __restrict__ A, const ushort* __restrict__ Bt,
        const float* __restrict__ bias, void* __restrict__ Cv,
        int M, int N, int K) {
    __shared__ ushort As[128 * 40];
    __shared__ ushort Bs[128 * 40];
    const int tid  = threadIdx.x;
    const int lane = tid & 63, wave = tid >> 6;
    const int wm = wave & 1, wn = wave >> 1;
    const int l15 = lane & 15, quad = lane >> 4;
    const int row0 = blockIdx.y * 128, col0 = blockIdx.x * 128;

    f32x4 acc[4][4];
#pragma unroll
    for (int i = 0; i < 4; ++i)
#pragma unroll
        for (int j = 0; j < 4; ++j) {
            f32x4 z = {0.f, 0.f, 0.f, 0.f};
            acc[i][j] = z;
        }

    const int c1 = tid, c2 = tid + 256;
    const int r1 = c1 >> 2, k1o = (c1 & 3) * 8;
    const int r2 = c2 >> 2, k2o = (c2 & 3) * 8;

    for (int k0 = 0; k0 < K; k0 += 32) {
        const bf16x8 a1 = *(const bf16x8*)&A [(size_t)(row0 + r1) * K + k0 + k1o];
        const bf16x8 a2 = *(const bf16x8*)&A [(size_t)(row0 + r2) * K + k0 + k2o];
        const bf16x8 b1 = *(const bf16x8*)&Bt[(size_t)(col0 + r1) * K + k0 + k1o];
        const bf16x8 b2 = *(const bf16x8*)&Bt[(size_t)(col0 + r2) * K + k0 + k2o];
        __syncthreads();
        *(bf16x8*)&As[r1 * 40 + k1o] = a1;
        *(bf16x8*)&As[r2 * 40 + k2o] = a2;
        *(bf16x8*)&Bs[r1 * 40 + k1o] = b1;
        *(bf16x8*)&Bs[r2 * 40 + k2o] = b2;
        __syncthreads();

        bf16x8 af[4], bf[4];
#pragma unroll
        for (int mi = 0; mi < 4; ++mi)
            af[mi] = *(const bf16x8*)&As[(wm * 64 + mi * 16 + l15) * 40 + quad * 8];
#pragma unroll
        for (int ni = 0; ni < 4; ++ni)
            bf[ni] = *(const bf16x8*)&Bs[(wn * 64 + ni * 16 + l15) * 40 + quad * 8];
#pragma unroll
        for (int mi = 0; mi < 4; ++mi)
#pragma unroll
            for (int ni = 0; ni < 4; ++ni)
                acc[mi][ni] = __builtin_amdgcn_mfma_f32_16x16x32_bf16(
                    af[mi], bf[ni], acc[mi][ni], 0, 0, 0);
    }

#pragma unroll
    for (int mi = 0; mi < 4; ++mi)
#pragma unroll
        for (int ni = 0; ni < 4; ++ni) {
            const int col = col0 + wn * 64 + ni * 16 + l15;
            const float bv = bias[col];
#pragma unroll
            for (int reg = 0; reg < 4; ++reg) {
                const int row = row0 + wm * 64 + mi * 16 + quad * 4 + reg;
                const float val = acc[mi][ni][reg] + bv;
                if (OUT_F32)
                    ((float*)Cv)[(size_t)row * N + col] = val;
                else
                    ((ushort*)Cv)[(size_t)row * N + col] = f32_to_bf16(val);
            }
        }
}

// ------------------------------------------------------ MFMA flash attention
// Block = 256 thr = 4 waves; block owns 64 q rows of one head (wave: 16 rows).
// Q A-frags in registers; K tile [key][d] and V^T tile [d][key] in LDS
// (72-short padded rows); online softmax in C-layout registers; P goes
// C-layout -> A-layout via per-wave LDS round trip.
__global__ __launch_bounds__(256) void gqa_attn_mfma(
        const ushort* __restrict__ Qb, const ushort* __restrict__ Kb,
        const ushort* __restrict__ Vt, ushort* __restrict__ Ab) {
    __shared__ ushort Ks[64 * 72];       // [key][d]
    __shared__ ushort Vs[64 * 72];       // [d][key]
    __shared__ ushort Ps[4][16 * 72];    // per-wave P [m][k]

    const int qt   = (int)(gridDim.x - 1 - blockIdx.x);   // heavy tiles first
    const int h    = blockIdx.y, g = h >> 2;
    const int tid  = threadIdx.x;
    const int lane = tid & 63, wave = tid >> 6;
    const int l15  = lane & 15, quad = lane >> 4;
    const int qr   = qt * 64 + wave * 16;     // wave's first q row

    // Q A-frags (held all kernel), k-steps d=0..31 / 32..63
    bf16x8 qa0, qa1;
    {
        const size_t base = (size_t)(qr + l15) * (NH * DK) + (size_t)h * DK + quad * 8;
        qa0 = *(const bf16x8*)&Qb[base];
        qa1 = *(const bf16x8*)&Qb[base + 32];
    }

    f32x4 o[4];
#pragma unroll
    for (int dt = 0; dt < 4; ++dt) { f32x4 z = {0.f,0.f,0.f,0.f}; o[dt] = z; }
    float mrow[4] = {-1e30f, -1e30f, -1e30f, -1e30f};
    float lrow[4] = {0.f, 0.f, 0.f, 0.f};

    for (int jt = 0; jt <= qt; ++jt) {
        const int j0 = jt * 64;
        __syncthreads();
        {   // stage K [key][d] and V^T [d][key] — 16 shorts per thread each
            const int row = tid >> 2, ch = tid & 3;
            const size_t kb = (size_t)(j0 + row) * (NG * DK) + g * DK + ch * 16;
            *(bf16x8*)&Ks[row * 72 + ch * 16]     = *(const bf16x8*)&Kb[kb];
            *(bf16x8*)&Ks[row * 72 + ch * 16 + 8] = *(const bf16x8*)&Kb[kb + 8];
            const size_t vb = (size_t)(g * 64 + row) * S_LEN + j0 + ch * 16;
            *(bf16x8*)&Vs[row * 72 + ch * 16]     = *(const bf16x8*)&Vt[vb];
            *(bf16x8*)&Vs[row * 72 + ch * 16 + 8] = *(const bf16x8*)&Vt[vb + 8];
        }
        __syncthreads();

        // S = Q K^T : 4 key tiles x 2 k-steps
        f32x4 s[4];
#pragma unroll
        for (int kt = 0; kt < 4; ++kt) {
            const bf16x8 kb0 = *(const bf16x8*)&Ks[(kt * 16 + l15) * 72 + quad * 8];
            const bf16x8 kb1 = *(const bf16x8*)&Ks[(kt * 16 + l15) * 72 + 32 + quad * 8];
            f32x4 acc = {0.f, 0.f, 0.f, 0.f};
            acc = __builtin_amdgcn_mfma_f32_16x16x32_bf16(qa0, kb0, acc, 0, 0, 0);
            acc = __builtin_amdgcn_mfma_f32_16x16x32_bf16(qa1, kb1, acc, 0, 0, 0);
            s[kt] = acc;
        }

        // scale + causal mask (diagonal tile only)
        if (jt == qt) {
#pragma unroll
            for (int kt = 0; kt < 4; ++kt)
#pragma unroll
                for (int r = 0; r < 4; ++r) {
                    const int key = kt * 16 + l15;                 // local
                    const int row = wave * 16 + quad * 4 + r;      // local
                    s[kt][r] = (key <= row) ? s[kt][r] * 0.125f : -1e30f;
                }
        } else {
#pragma unroll
            for (int kt = 0; kt < 4; ++kt)
#pragma unroll
                for (int r = 0; r < 4; ++r) s[kt][r] *= 0.125f;
        }

        // online softmax (rows live in regs: row = quad*4 + r)
        float rmax[4];
#pragma unroll
        for (int r = 0; r < 4; ++r)
            rmax[r] = fmaxf(fmaxf(s[0][r], s[1][r]), fmaxf(s[2][r], s[3][r]));
#pragma unroll
        for (int off = 1; off <= 8; off <<= 1)
#pragma unroll
            for (int r = 0; r < 4; ++r)
                rmax[r] = fmaxf(rmax[r], __shfl_xor(rmax[r], off, 64));

        float alpha[4];
#pragma unroll
        for (int r = 0; r < 4; ++r) {
            const float mn = fmaxf(mrow[r], rmax[r]);
            alpha[r] = __expf(mrow[r] - mn);
            mrow[r] = mn;
        }

        float p[4][4], rsum[4];
#pragma unroll
        for (int kt = 0; kt < 4; ++kt)
#pragma unroll
            for (int r = 0; r < 4; ++r)
                p[kt][r] = __expf(s[kt][r] - mrow[r]);
#pragma unroll
        for (int r = 0; r < 4; ++r)
            rsum[r] = (p[0][r] + p[1][r]) + (p[2][r] + p[3][r]);
#pragma unroll
        for (int off = 1; off <= 8; off <<= 1)
#pragma unroll
            for (int r = 0; r < 4; ++r)
                rsum[r] += __shfl_xor(rsum[r], off, 64);
#pragma unroll
        for (int r = 0; r < 4; ++r)
            lrow[r] = lrow[r] * alpha[r] + rsum[r];
#pragma unroll
        for (int dt = 0; dt < 4; ++dt)
#pragma unroll
            for (int r = 0; r < 4; ++r)
                o[dt][r] *= alpha[r];

        // P: C-layout -> A-layout via per-wave LDS region
        ushort* Pw = &Ps[wave][0];
#pragma unroll
        for (int kt = 0; kt < 4; ++kt)
#pragma unroll
            for (int r = 0; r < 4; ++r)
                Pw[(quad * 4 + r) * 72 + kt * 16 + l15] = f32_to_bf16(p[kt][r]);
        const bf16x8 pa0 = *(const bf16x8*)&Pw[l15 * 72 + quad * 8];
        const bf16x8 pa1 = *(const bf16x8*)&Pw[l15 * 72 + 32 + quad * 8];

        // O += P V : keys 0..31 / 32..63, 4 d tiles
#pragma unroll
        for (int dt = 0; dt < 4; ++dt) {
            const bf16x8 vb0 = *(const bf16x8*)&Vs[(dt * 16 + l15) * 72 + quad * 8];
            const bf16x8 vb1 = *(const bf16x8*)&Vs[(dt * 16 + l15) * 72 + 32 + quad * 8];
            o[dt] = __builtin_amdgcn_mfma_f32_16x16x32_bf16(pa0, vb0, o[dt], 0, 0, 0);
            o[dt] = __builtin_amdgcn_mfma_f32_16x16x32_bf16(pa1, vb1, o[dt], 0, 0, 0);
        }
    }

    float inv[4];
#pragma unroll
    for (int r = 0; r < 4; ++r) inv[r] = 1.0f / lrow[r];
#pragma unroll
    for (int dt = 0; dt < 4; ++dt)
#pragma unroll
        for (int r = 0; r < 4; ++r)
            Ab[(size_t)(qr + quad * 4 + r) * (NH * DV) + (size_t)h * DV + dt * 16 + l15] =
                f32_to_bf16(o[dt][r] * inv[r]);
}

// ---------------------------------------------------------------------------
extern "C" void kernel_launch(void* const* d_in, const int* in_sizes, int n_in,
                              void* d_out, int out_size, void* d_ws, size_t ws_size,
                              hipStream_t stream) {
    const float* queries = (const float*)d_in[0];
    const float* keys    = (const float*)d_in[1];
    const float* values  = (const float*)d_in[2];
    const float* Wq      = (const float*)d_in[3];
    const float* bq      = (const float*)d_in[4];
    const float* Wk      = (const float*)d_in[5];
    const float* bk      = (const float*)d_in[6];
    const float* Wv      = (const float*)d_in[7];
    const float* bv      = (const float*)d_in[8];
    const float* Wo      = (const float*)d_in[9];
    const float* bo      = (const float*)d_in[10];
    float* out = (float*)d_out;

    const size_t MB = 1024 * 1024;
    unsigned char* w = (unsigned char*)d_ws;
    ushort* Xq  = (ushort*)(w + 0 * MB);    // [2048][2048] bf16
    ushort* Xk  = (ushort*)(w + 8 * MB);
    ushort* Xv  = (ushort*)(w + 16 * MB);
    ushort* Wqt = (ushort*)(w + 24 * MB);   // [2048][2048]
    ushort* Wkt = (ushort*)(w + 32 * MB);   // [512][2048]
    ushort* Wvt = (ushort*)(w + 34 * MB);
    ushort* Wot = (ushort*)(w + 36 * MB);   // [2048][2048]
    ushort* Qb  = (ushort*)(w + 44 * MB);   // [2048][2048]
    ushort* Kb  = (ushort*)(w + 52 * MB);   // [2048][512]
    ushort* Vb  = (ushort*)(w + 54 * MB);
    ushort* Ab  = (ushort*)(w + 56 * MB);   // [2048][2048]
    // V^T [512][2048] reuses the Xk region (dead after the K projection)
    ushort* Vtp = (ushort*)(w + 8 * MB);

    const int n8 = (S_LEN * DMODEL) / 8;
    cast_f32_to_bf16<<<1024, 256, 0, stream>>>(queries, Xq, n8);
    cast_f32_to_bf16<<<1024, 256, 0, stream>>>(keys,    Xk, n8);
    cast_f32_to_bf16<<<1024, 256, 0, stream>>>(values,  Xv, n8);

    dim3 tb(32, 8);
    transpose_cast_bf16<<<dim3(2048 / 32, 2048 / 32), tb, 0, stream>>>(Wq, Wqt, DMODEL, 2048);
    transpose_cast_bf16<<<dim3(512 / 32,  2048 / 32), tb, 0, stream>>>(Wk, Wkt, DMODEL, 512);
    transpose_cast_bf16<<<dim3(512 / 32,  2048 / 32), tb, 0, stream>>>(Wv, Wvt, DMODEL, 512);
    transpose_cast_bf16<<<dim3(2048 / 32, 2048 / 32), tb, 0, stream>>>(Wo, Wot, DMODEL, 2048);

    gemm_bf16_mfma<false><<<dim3(2048 / 128, 2048 / 128), 256, 0, stream>>>(
        Xq, Wqt, bq, Qb, S_LEN, 2048, DMODEL);
    gemm_bf16_mfma<false><<<dim3(512 / 128, 2048 / 128), 256, 0, stream>>>(
        Xk, Wkt, bk, Kb, S_LEN, 512, DMODEL);
    gemm_bf16_mfma<false><<<dim3(512 / 128, 2048 / 128), 256, 0, stream>>>(
        Xv, Wvt, bv, Vb, S_LEN, 512, DMODEL);

    // V [2048][512] -> V^T [512][2048]
    transpose_bf16<<<dim3(512 / 32, 2048 / 32), tb, 0, stream>>>(Vb, Vtp, S_LEN, 512);

    gqa_attn_mfma<<<dim3(32, 32), 256, 0, stream>>>(Qb, Kb, Vtp, Ab);

    gemm_bf16_mfma<true><<<dim3(2048 / 128, 2048 / 128), 256, 0, stream>>>(
        Ab, Wot, bo, out, S_LEN, DMODEL, DMODEL);
}

// Round 6
// 450.064 us; speedup vs baseline: 16.1681x; 1.0503x over previous
//
#include <hip/hip_runtime.h>
#include <hip/hip_bf16.h>

#define S_LEN  2048
#define DMODEL 2048
#define NH     32
#define NG     8
#define DK     64
#define DV     64

typedef short bf16x8 __attribute__((ext_vector_type(8)));
typedef float f32x4  __attribute__((ext_vector_type(4)));

__device__ __forceinline__ ushort f32_to_bf16(float f) {
    uint u = __float_as_uint(f);
    return (ushort)((u + 0x7fffu + ((u >> 16) & 1u)) >> 16);   // RNE
}
__device__ __forceinline__ float bf16_to_f32(ushort h) {
    return __uint_as_float(((uint)h) << 16);
}

// ---------------------------------------------------------------- cast f32->bf16
__global__ void cast_f32_to_bf16(const float* __restrict__ in,
                                 ushort* __restrict__ out, int n8) {
    int i = blockIdx.x * blockDim.x + threadIdx.x;
    const int stride = gridDim.x * blockDim.x;
    for (; i < n8; i += stride) {
        const float4 a = ((const float4*)in)[2 * i];
        const float4 b = ((const float4*)in)[2 * i + 1];
        uint4 o;
        o.x = (uint)f32_to_bf16(a.x) | ((uint)f32_to_bf16(a.y) << 16);
        o.y = (uint)f32_to_bf16(a.z) | ((uint)f32_to_bf16(a.w) << 16);
        o.z = (uint)f32_to_bf16(b.x) | ((uint)f32_to_bf16(b.y) << 16);
        o.w = (uint)f32_to_bf16(b.z) | ((uint)f32_to_bf16(b.w) << 16);
        ((uint4*)out)[i] = o;
    }
}

// ------------------------------------------------- W[K][N] f32 -> Wt[N][K] bf16
__global__ void transpose_cast_bf16(const float* __restrict__ W,
                                    ushort* __restrict__ Wt, int K, int N) {
    __shared__ float t[32][33];
    const int n0 = blockIdx.x * 32, k0 = blockIdx.y * 32;
    const int tx = threadIdx.x, ty = threadIdx.y;   // 32 x 8
#pragma unroll
    for (int i = 0; i < 4; ++i)
        t[ty + 8 * i][tx] = W[(size_t)(k0 + ty + 8 * i) * N + n0 + tx];
    __syncthreads();
#pragma unroll
    for (int i = 0; i < 4; ++i)
        Wt[(size_t)(n0 + ty + 8 * i) * K + k0 + tx] = f32_to_bf16(t[tx][ty + 8 * i]);
}

// --------------------------------------------- bf16 [R][C] -> [C][R] transpose
__global__ void transpose_bf16(const ushort* __restrict__ in,
                               ushort* __restrict__ out, int R, int C) {
    __shared__ ushort t[32][34];
    const int c0 = blockIdx.x * 32, r0 = blockIdx.y * 32;
    const int tx = threadIdx.x, ty = threadIdx.y;   // 32 x 8
#pragma unroll
    for (int i = 0; i < 4; ++i)
        t[ty + 8 * i][tx] = in[(size_t)(r0 + ty + 8 * i) * C + c0 + tx];
    __syncthreads();
#pragma unroll
    for (int i = 0; i < 4; ++i)
        out[(size_t)(c0 + ty + 8 * i) * R + r0 + tx] = t[tx][ty + 8 * i];
}

// ------------------------------------------------------------- bf16 MFMA GEMM
// C[M][N] = A[M][K] @ Bt[N][K]^T + bias.  128x128 tile, 4 waves (2x2 of 64x64),
// each wave 4x4 frags of mfma_f32_16x16x32_bf16.
template <bool OUT_F32>
__global__ __launch_bounds__(256) void gemm_bf16_mfma(
        const ushort* __restrict__ A, const ushort* __restrict__ Bt,
        const float* __restrict__ bias, void* __restrict__ Cv,
        int M, int N, int K) {
    __shared__ ushort As[128 * 40];
    __shared__ ushort Bs[128 * 40];
    const int tid  = threadIdx.x;
    const int lane = tid & 63, wave = tid >> 6;
    const int wm = wave & 1, wn = wave >> 1;
    const int l15 = lane & 15, quad = lane >> 4;
    const int row0 = blockIdx.y * 128, col0 = blockIdx.x * 128;

    f32x4 acc[4][4];
#pragma unroll
    for (int i = 0; i < 4; ++i)
#pragma unroll
        for (int j = 0; j < 4; ++j) {
            f32x4 z = {0.f, 0.f, 0.f, 0.f};
            acc[i][j] = z;
        }

    const int c1 = tid, c2 = tid + 256;
    const int r1 = c1 >> 2, k1o = (c1 & 3) * 8;
    const int r2 = c2 >> 2, k2o = (c2 & 3) * 8;

    for (int k0 = 0; k0 < K; k0 += 32) {
        const bf16x8 a1 = *(const bf16x8*)&A [(size_t)(row0 + r1) * K + k0 + k1o];
        const bf16x8 a2 = *(const bf16x8*)&A [(size_t)(row0 + r2) * K + k0 + k2o];
        const bf16x8 b1 = *(const bf16x8*)&Bt[(size_t)(col0 + r1) * K + k0 + k1o];
        const bf16x8 b2 = *(const bf16x8*)&Bt[(size_t)(col0 + r2) * K + k0 + k2o];
        __syncthreads();
        *(bf16x8*)&As[r1 * 40 + k1o] = a1;
        *(bf16x8*)&As[r2 * 40 + k2o] = a2;
        *(bf16x8*)&Bs[r1 * 40 + k1o] = b1;
        *(bf16x8*)&Bs[r2 * 40 + k2o] = b2;
        __syncthreads();

        bf16x8 af[4], bf[4];
#pragma unroll
        for (int mi = 0; mi < 4; ++mi)
            af[mi] = *(const bf16x8*)&As[(wm * 64 + mi * 16 + l15) * 40 + quad * 8];
#pragma unroll
        for (int ni = 0; ni < 4; ++ni)
            bf[ni] = *(const bf16x8*)&Bs[(wn * 64 + ni * 16 + l15) * 40 + quad * 8];
#pragma unroll
        for (int mi = 0; mi < 4; ++mi)
#pragma unroll
            for (int ni = 0; ni < 4; ++ni)
                acc[mi][ni] = __builtin_amdgcn_mfma_f32_16x16x32_bf16(
                    af[mi], bf[ni], acc[mi][ni], 0, 0, 0);
    }

#pragma unroll
    for (int mi = 0; mi < 4; ++mi)
#pragma unroll
        for (int ni = 0; ni < 4; ++ni) {
            const int col = col0 + wn * 64 + ni * 16 + l15;
            const float bv = bias[col];
#pragma unroll
            for (int reg = 0; reg < 4; ++reg) {
                const int row = row0 + wm * 64 + mi * 16 + quad * 4 + reg;
                const float val = acc[mi][ni][reg] + bv;
                if (OUT_F32)
                    ((float*)Cv)[(size_t)row * N + col] = val;
                else
                    ((ushort*)Cv)[(size_t)row * N + col] = f32_to_bf16(val);
            }
        }
}

// ------------------------------------------------------ MFMA flash attention
// Block = 256 thr = 4 waves; block owns 64 q rows of one head (wave: 16 rows).
// Q A-frags in registers; K tile [key][d] and V^T tile [d][key] in LDS
// (72-short padded rows); online softmax in C-layout registers; P goes
// C-layout -> A-layout via per-wave LDS round trip.
// K/V staging is software-pipelined: tile jt+1 is global-loaded into VGPRs
// during tile jt's compute; the barrier's vmcnt drain lands after compute.
__global__ __launch_bounds__(256) void gqa_attn_mfma(
        const ushort* __restrict__ Qb, const ushort* __restrict__ Kb,
        const ushort* __restrict__ Vt, ushort* __restrict__ Ab) {
    __shared__ ushort Ks[64 * 72];       // [key][d]
    __shared__ ushort Vs[64 * 72];       // [d][key]
    __shared__ ushort Ps[4][16 * 72];    // per-wave P [m][k]

    const int qt   = (int)(gridDim.x - 1 - blockIdx.x);   // heavy tiles first
    const int h    = blockIdx.y, g = h >> 2;
    const int tid  = threadIdx.x;
    const int lane = tid & 63, wave = tid >> 6;
    const int l15  = lane & 15, quad = lane >> 4;
    const int qr   = qt * 64 + wave * 16;     // wave's first q row

    // Q A-frags (held all kernel), k-steps d=0..31 / 32..63
    bf16x8 qa0, qa1;
    {
        const size_t base = (size_t)(qr + l15) * (NH * DK) + (size_t)h * DK + quad * 8;
        qa0 = *(const bf16x8*)&Qb[base];
        qa1 = *(const bf16x8*)&Qb[base + 32];
    }

    f32x4 o[4];
#pragma unroll
    for (int dt = 0; dt < 4; ++dt) { f32x4 z = {0.f,0.f,0.f,0.f}; o[dt] = z; }
    float mrow[4] = {-1e30f, -1e30f, -1e30f, -1e30f};
    float lrow[4] = {0.f, 0.f, 0.f, 0.f};

    // per-thread staging coordinates (fixed across tiles)
    const int srow = tid >> 2, sch = tid & 3;
    const ushort* kbase = Kb + (size_t)srow * (NG * DK) + g * DK + sch * 16;
    const ushort* vbase = Vt + (size_t)(g * 64 + srow) * S_LEN + sch * 16;

    // preload tile 0 into registers
    bf16x8 kr0 = *(const bf16x8*)(kbase);
    bf16x8 kr1 = *(const bf16x8*)(kbase + 8);
    bf16x8 vr0 = *(const bf16x8*)(vbase);
    bf16x8 vr1 = *(const bf16x8*)(vbase + 8);

    for (int jt = 0; jt <= qt; ++jt) {
        __syncthreads();                 // prev tile's LDS reads complete
        {   // store prefetched K/V regs -> LDS
            *(bf16x8*)&Ks[srow * 72 + sch * 16]     = kr0;
            *(bf16x8*)&Ks[srow * 72 + sch * 16 + 8] = kr1;
            *(bf16x8*)&Vs[srow * 72 + sch * 16]     = vr0;
            *(bf16x8*)&Vs[srow * 72 + sch * 16 + 8] = vr1;
        }
        __syncthreads();

        // issue prefetch of tile jt+1 (completes during compute below)
        if (jt < qt) {
            const size_t ko = (size_t)(jt + 1) * 64 * (NG * DK);
            const size_t vo = (size_t)(jt + 1) * 64;
            kr0 = *(const bf16x8*)(kbase + ko);
            kr1 = *(const bf16x8*)(kbase + ko + 8);
            vr0 = *(const bf16x8*)(vbase + vo);
            vr1 = *(const bf16x8*)(vbase + vo + 8);
        }

        // S = Q K^T : 4 key tiles x 2 k-steps
        f32x4 s[4];
#pragma unroll
        for (int kt = 0; kt < 4; ++kt) {
            const bf16x8 kb0 = *(const bf16x8*)&Ks[(kt * 16 + l15) * 72 + quad * 8];
            const bf16x8 kb1 = *(const bf16x8*)&Ks[(kt * 16 + l15) * 72 + 32 + quad * 8];
            f32x4 acc = {0.f, 0.f, 0.f, 0.f};
            acc = __builtin_amdgcn_mfma_f32_16x16x32_bf16(qa0, kb0, acc, 0, 0, 0);
            acc = __builtin_amdgcn_mfma_f32_16x16x32_bf16(qa1, kb1, acc, 0, 0, 0);
            s[kt] = acc;
        }

        // scale + causal mask (diagonal tile only)
        if (jt == qt) {
#pragma unroll
            for (int kt = 0; kt < 4; ++kt)
#pragma unroll
                for (int r = 0; r < 4; ++r) {
                    const int key = kt * 16 + l15;                 // local
                    const int row = wave * 16 + quad * 4 + r;      // local
                    s[kt][r] = (key <= row) ? s[kt][r] * 0.125f : -1e30f;
                }
        } else {
#pragma unroll
            for (int kt = 0; kt < 4; ++kt)
#pragma unroll
                for (int r = 0; r < 4; ++r) s[kt][r] *= 0.125f;
        }

        // online softmax (rows live in regs: row = quad*4 + r)
        float rmax[4];
#pragma unroll
        for (int r = 0; r < 4; ++r)
            rmax[r] = fmaxf(fmaxf(s[0][r], s[1][r]), fmaxf(s[2][r], s[3][r]));
#pragma unroll
        for (int off = 1; off <= 8; off <<= 1)
#pragma unroll
            for (int r = 0; r < 4; ++r)
                rmax[r] = fmaxf(rmax[r], __shfl_xor(rmax[r], off, 64));

        float alpha[4];
#pragma unroll
        for (int r = 0; r < 4; ++r) {
            const float mn = fmaxf(mrow[r], rmax[r]);
            alpha[r] = __expf(mrow[r] - mn);
            mrow[r] = mn;
        }

        float p[4][4], rsum[4];
#pragma unroll
        for (int kt = 0; kt < 4; ++kt)
#pragma unroll
            for (int r = 0; r < 4; ++r)
                p[kt][r] = __expf(s[kt][r] - mrow[r]);
#pragma unroll
        for (int r = 0; r < 4; ++r)
            rsum[r] = (p[0][r] + p[1][r]) + (p[2][r] + p[3][r]);
#pragma unroll
        for (int off = 1; off <= 8; off <<= 1)
#pragma unroll
            for (int r = 0; r < 4; ++r)
                rsum[r] += __shfl_xor(rsum[r], off, 64);
#pragma unroll
        for (int r = 0; r < 4; ++r)
            lrow[r] = lrow[r] * alpha[r] + rsum[r];
#pragma unroll
        for (int dt = 0; dt < 4; ++dt)
#pragma unroll
            for (int r = 0; r < 4; ++r)
                o[dt][r] *= alpha[r];

        // P: C-layout -> A-layout via per-wave LDS region
        ushort* Pw = &Ps[wave][0];
#pragma unroll
        for (int kt = 0; kt < 4; ++kt)
#pragma unroll
            for (int r = 0; r < 4; ++r)
                Pw[(quad * 4 + r) * 72 + kt * 16 + l15] = f32_to_bf16(p[kt][r]);
        const bf16x8 pa0 = *(const bf16x8*)&Pw[l15 * 72 + quad * 8];
        const bf16x8 pa1 = *(const bf16x8*)&Pw[l15 * 72 + 32 + quad * 8];

        // O += P V : keys 0..31 / 32..63, 4 d tiles
#pragma unroll
        for (int dt = 0; dt < 4; ++dt) {
            const bf16x8 vb0 = *(const bf16x8*)&Vs[(dt * 16 + l15) * 72 + quad * 8];
            const bf16x8 vb1 = *(const bf16x8*)&Vs[(dt * 16 + l15) * 72 + 32 + quad * 8];
            o[dt] = __builtin_amdgcn_mfma_f32_16x16x32_bf16(pa0, vb0, o[dt], 0, 0, 0);
            o[dt] = __builtin_amdgcn_mfma_f32_16x16x32_bf16(pa1, vb1, o[dt], 0, 0, 0);
        }
    }

    float inv[4];
#pragma unroll
    for (int r = 0; r < 4; ++r) inv[r] = 1.0f / lrow[r];
#pragma unroll
    for (int dt = 0; dt < 4; ++dt)
#pragma unroll
        for (int r = 0; r < 4; ++r)
            Ab[(size_t)(qr + quad * 4 + r) * (NH * DV) + (size_t)h * DV + dt * 16 + l15] =
                f32_to_bf16(o[dt][r] * inv[r]);
}

// ---------------------------------------------------------------------------
extern "C" void kernel_launch(void* const* d_in, const int* in_sizes, int n_in,
                              void* d_out, int out_size, void* d_ws, size_t ws_size,
                              hipStream_t stream) {
    const float* queries = (const float*)d_in[0];
    const float* keys    = (const float*)d_in[1];
    const float* values  = (const float*)d_in[2];
    const float* Wq      = (const float*)d_in[3];
    const float* bq      = (const float*)d_in[4];
    const float* Wk      = (const float*)d_in[5];
    const float* bk      = (const float*)d_in[6];
    const float* Wv      = (const float*)d_in[7];
    const float* bv      = (const float*)d_in[8];
    const float* Wo      = (const float*)d_in[9];
    const float* bo      = (const float*)d_in[10];
    float* out = (float*)d_out;

    const size_t MB = 1024 * 1024;
    unsigned char* w = (unsigned char*)d_ws;
    ushort* Xq  = (ushort*)(w + 0 * MB);    // [2048][2048] bf16
    ushort* Xk  = (ushort*)(w + 8 * MB);
    ushort* Xv  = (ushort*)(w + 16 * MB);
    ushort* Wqt = (ushort*)(w + 24 * MB);   // [2048][2048]
    ushort* Wkt = (ushort*)(w + 32 * MB);   // [512][2048]
    ushort* Wvt = (ushort*)(w + 34 * MB);
    ushort* Wot = (ushort*)(w + 36 * MB);   // [2048][2048]
    ushort* Qb  = (ushort*)(w + 44 * MB);   // [2048][2048]
    ushort* Kb  = (ushort*)(w + 52 * MB);   // [2048][512]
    ushort* Vb  = (ushort*)(w + 54 * MB);
    ushort* Ab  = (ushort*)(w + 56 * MB);   // [2048][2048]
    // V^T [512][2048] reuses the Xk region (dead after the K projection)
    ushort* Vtp = (ushort*)(w + 8 * MB);

    const int n8 = (S_LEN * DMODEL) / 8;
    cast_f32_to_bf16<<<1024, 256, 0, stream>>>(queries, Xq, n8);
    cast_f32_to_bf16<<<1024, 256, 0, stream>>>(keys,    Xk, n8);
    cast_f32_to_bf16<<<1024, 256, 0, stream>>>(values,  Xv, n8);

    dim3 tb(32, 8);
    transpose_cast_bf16<<<dim3(2048 / 32, 2048 / 32), tb, 0, stream>>>(Wq, Wqt, DMODEL, 2048);
    transpose_cast_bf16<<<dim3(512 / 32,  2048 / 32), tb, 0, stream>>>(Wk, Wkt, DMODEL, 512);
    transpose_cast_bf16<<<dim3(512 / 32,  2048 / 32), tb, 0, stream>>>(Wv, Wvt, DMODEL, 512);
    transpose_cast_bf16<<<dim3(2048 / 32, 2048 / 32), tb, 0, stream>>>(Wo, Wot, DMODEL, 2048);

    gemm_bf16_mfma<false><<<dim3(2048 / 128, 2048 / 128), 256, 0, stream>>>(
        Xq, Wqt, bq, Qb, S_LEN, 2048, DMODEL);
    gemm_bf16_mfma<false><<<dim3(512 / 128, 2048 / 128), 256, 0, stream>>>(
        Xk, Wkt, bk, Kb, S_LEN, 512, DMODEL);
    gemm_bf16_mfma<false><<<dim3(512 / 128, 2048 / 128), 256, 0, stream>>>(
        Xv, Wvt, bv, Vb, S_LEN, 512, DMODEL);

    // V [2048][512] -> V^T [512][2048]
    transpose_bf16<<<dim3(512 / 32, 2048 / 32), tb, 0, stream>>>(Vb, Vtp, S_LEN, 512);

    gqa_attn_mfma<<<dim3(32, 32), 256, 0, stream>>>(Qb, Kb, Vtp, Ab);

    gemm_bf16_mfma<true><<<dim3(2048 / 128, 2048 / 128), 256, 0, stream>>>(
        Ab, Wot, bo, out, S_LEN, DMODEL, DMODEL);
}

// Round 7
// 324.170 us; speedup vs baseline: 22.4472x; 1.3884x over previous
//
#include <hip/hip_runtime.h>
#include <hip/hip_bf16.h>

#define S_LEN  2048
#define DMODEL 2048
#define NH     32
#define NG     8
#define DK     64
#define DV     64

typedef short bf16x8 __attribute__((ext_vector_type(8)));
typedef float f32x4  __attribute__((ext_vector_type(4)));

__device__ __forceinline__ ushort f32_to_bf16(float f) {
    uint u = __float_as_uint(f);
    return (ushort)((u + 0x7fffu + ((u >> 16) & 1u)) >> 16);   // RNE
}
__device__ __forceinline__ float bf16_to_f32(ushort h) {
    return __uint_as_float(((uint)h) << 16);
}

// ---------------------------------------------------------------- cast f32->bf16
__global__ void cast_f32_to_bf16(const float* __restrict__ in,
                                 ushort* __restrict__ out, int n8) {
    int i = blockIdx.x * blockDim.x + threadIdx.x;
    const int stride = gridDim.x * blockDim.x;
    for (; i < n8; i += stride) {
        const float4 a = ((const float4*)in)[2 * i];
        const float4 b = ((const float4*)in)[2 * i + 1];
        uint4 o;
        o.x = (uint)f32_to_bf16(a.x) | ((uint)f32_to_bf16(a.y) << 16);
        o.y = (uint)f32_to_bf16(a.z) | ((uint)f32_to_bf16(a.w) << 16);
        o.z = (uint)f32_to_bf16(b.x) | ((uint)f32_to_bf16(b.y) << 16);
        o.w = (uint)f32_to_bf16(b.z) | ((uint)f32_to_bf16(b.w) << 16);
        ((uint4*)out)[i] = o;
    }
}

// ------------------------------------------------- W[K][N] f32 -> Wt[N][K] bf16
__global__ void transpose_cast_bf16(const float* __restrict__ W,
                                    ushort* __restrict__ Wt, int K, int N) {
    __shared__ float t[32][33];
    const int n0 = blockIdx.x * 32, k0 = blockIdx.y * 32;
    const int tx = threadIdx.x, ty = threadIdx.y;   // 32 x 8
#pragma unroll
    for (int i = 0; i < 4; ++i)
        t[ty + 8 * i][tx] = W[(size_t)(k0 + ty + 8 * i) * N + n0 + tx];
    __syncthreads();
#pragma unroll
    for (int i = 0; i < 4; ++i)
        Wt[(size_t)(n0 + ty + 8 * i) * K + k0 + tx] = f32_to_bf16(t[tx][ty + 8 * i]);
}

// --------------------------------------------- bf16 [R][C] -> [C][R] transpose
__global__ void transpose_bf16(const ushort* __restrict__ in,
                               ushort* __restrict__ out, int R, int C) {
    __shared__ ushort t[32][34];
    const int c0 = blockIdx.x * 32, r0 = blockIdx.y * 32;
    const int tx = threadIdx.x, ty = threadIdx.y;   // 32 x 8
#pragma unroll
    for (int i = 0; i < 4; ++i)
        t[ty + 8 * i][tx] = in[(size_t)(r0 + ty + 8 * i) * C + c0 + tx];
    __syncthreads();
#pragma unroll
    for (int i = 0; i < 4; ++i)
        out[(size_t)(c0 + ty + 8 * i) * R + r0 + tx] = t[tx][ty + 8 * i];
}

// ------------------------------------------------------------- bf16 MFMA GEMM
// C[M][N] = A[M][K] @ Bt[N][K]^T + bias.  128(M)x64(N) tile, 4 waves stacked
// in M (each: 32 rows x 64 cols = 2x4 frags of mfma_f32_16x16x32_bf16).
// LDS row stride 40 shorts (2-way bank alias only). Register-prefetch
// pipeline: next k-tile's global loads issue before compute.
template <bool OUT_F32>
__device__ __forceinline__ void gemm_body_128x64(
        const ushort* __restrict__ A, const ushort* __restrict__ Bt,
        const float* __restrict__ bias, void* __restrict__ Cv,
        ushort* As, ushort* Bs, int N, int K) {
    const int tid  = threadIdx.x;
    const int lane = tid & 63, wave = tid >> 6;
    const int l15 = lane & 15, quad = lane >> 4;
    const int row0 = blockIdx.y * 128, col0 = blockIdx.x * 64;

    f32x4 acc[2][4];
#pragma unroll
    for (int i = 0; i < 2; ++i)
#pragma unroll
        for (int j = 0; j < 4; ++j) { f32x4 z = {0.f,0.f,0.f,0.f}; acc[i][j] = z; }

    // staging coords: A 128x32 (2 b128/thread), B 64x32 (1 b128/thread)
    const int ar = tid >> 1, ak = (tid & 1) * 16;
    const int br = tid >> 2, bk = (tid & 3) * 8;
    const ushort* aptr = A  + (size_t)(row0 + ar) * K + ak;
    const ushort* bptr = Bt + (size_t)(col0 + br) * K + bk;

    bf16x8 a0 = *(const bf16x8*)(aptr);
    bf16x8 a1 = *(const bf16x8*)(aptr + 8);
    bf16x8 b0 = *(const bf16x8*)(bptr);

    for (int k0 = 0; k0 < K; k0 += 32) {
        __syncthreads();
        *(bf16x8*)&As[ar * 40 + ak]     = a0;
        *(bf16x8*)&As[ar * 40 + ak + 8] = a1;
        *(bf16x8*)&Bs[br * 40 + bk]     = b0;
        __syncthreads();

        if (k0 + 32 < K) {
            a0 = *(const bf16x8*)(aptr + k0 + 32);
            a1 = *(const bf16x8*)(aptr + k0 + 40);
            b0 = *(const bf16x8*)(bptr + k0 + 32);
        }

        bf16x8 af[2], bf[4];
#pragma unroll
        for (int mi = 0; mi < 2; ++mi)
            af[mi] = *(const bf16x8*)&As[(wave * 32 + mi * 16 + l15) * 40 + quad * 8];
#pragma unroll
        for (int ni = 0; ni < 4; ++ni)
            bf[ni] = *(const bf16x8*)&Bs[(ni * 16 + l15) * 40 + quad * 8];
#pragma unroll
        for (int mi = 0; mi < 2; ++mi)
#pragma unroll
            for (int ni = 0; ni < 4; ++ni)
                acc[mi][ni] = __builtin_amdgcn_mfma_f32_16x16x32_bf16(
                    af[mi], bf[ni], acc[mi][ni], 0, 0, 0);
    }

#pragma unroll
    for (int mi = 0; mi < 2; ++mi)
#pragma unroll
        for (int ni = 0; ni < 4; ++ni) {
            const int col = col0 + ni * 16 + l15;
            const float bv = bias[col];
#pragma unroll
            for (int reg = 0; reg < 4; ++reg) {
                const int row = row0 + wave * 32 + mi * 16 + quad * 4 + reg;
                const float val = acc[mi][ni][reg] + bv;
                if (OUT_F32)
                    ((float*)Cv)[(size_t)row * N + col] = val;
                else
                    ((ushort*)Cv)[(size_t)row * N + col] = f32_to_bf16(val);
            }
        }
}

template <bool OUT_F32>
__global__ __launch_bounds__(256) void gemm_bf16_v2(
        const ushort* __restrict__ A, const ushort* __restrict__ Bt,
        const float* __restrict__ bias, void* __restrict__ Cv, int N, int K) {
    __shared__ ushort As[128 * 40];
    __shared__ ushort Bs[64 * 40];
    gemm_body_128x64<OUT_F32>(A, Bt, bias, Cv, As, Bs, N, K);
}

// K and V projections fused via gridDim.z
__global__ __launch_bounds__(256) void gemm_kv(
        const ushort* __restrict__ Xk, const ushort* __restrict__ Xv,
        const ushort* __restrict__ Wkt, const ushort* __restrict__ Wvt,
        const float* __restrict__ bk, const float* __restrict__ bv,
        ushort* __restrict__ Kb, ushort* __restrict__ Vb, int N, int K) {
    __shared__ ushort As[128 * 40];
    __shared__ ushort Bs[64 * 40];
    if (blockIdx.z == 0)
        gemm_body_128x64<false>(Xk, Wkt, bk, Kb, As, Bs, N, K);
    else
        gemm_body_128x64<false>(Xv, Wvt, bv, Vb, As, Bs, N, K);
}

// ------------------------------------------------------ MFMA flash attention
// Grid (16, 32): block handles q-tiles {bx, 31-bx} of one head sequentially —
// exactly 33 j-tiles per block (perfect causal load balance), 512 blocks.
// 4 waves/block; wave owns a 16-row Q stripe. Q A-frags in registers; K tile
// [key][d] and V^T tile [d][key] in LDS (72-short padded); online softmax in
// C-layout registers; P C->A layout via per-wave LDS; K/V reg-prefetch.
__global__ __launch_bounds__(256) void gqa_attn_mfma(
        const ushort* __restrict__ Qb, const ushort* __restrict__ Kb,
        const ushort* __restrict__ Vt, ushort* __restrict__ Ab) {
    __shared__ ushort Ks[64 * 72];       // [key][d]
    __shared__ ushort Vs[64 * 72];       // [d][key]
    __shared__ ushort Ps[4][16 * 72];    // per-wave P [m][k]

    const int h    = blockIdx.y, g = h >> 2;
    const int tid  = threadIdx.x;
    const int lane = tid & 63, wave = tid >> 6;
    const int l15  = lane & 15, quad = lane >> 4;
    const int NT   = S_LEN / 64;         // 32 q-tiles

    // per-thread staging coordinates (fixed across tiles)
    const int srow = tid >> 2, sch = tid & 3;
    const ushort* kbase = Kb + (size_t)srow * (NG * DK) + g * DK + sch * 16;
    const ushort* vbase = Vt + (size_t)(g * 64 + srow) * S_LEN + sch * 16;

    for (int sel = 0; sel < 2; ++sel) {
        const int qt = sel ? (NT - 1 - (int)blockIdx.x) : (int)blockIdx.x;
        const int qr = qt * 64 + wave * 16;      // wave's first q row

        // Q A-frags, k-steps d=0..31 / 32..63
        bf16x8 qa0, qa1;
        {
            const size_t base = (size_t)(qr + l15) * (NH * DK) + (size_t)h * DK + quad * 8;
            qa0 = *(const bf16x8*)&Qb[base];
            qa1 = *(const bf16x8*)&Qb[base + 32];
        }

        f32x4 o[4];
#pragma unroll
        for (int dt = 0; dt < 4; ++dt) { f32x4 z = {0.f,0.f,0.f,0.f}; o[dt] = z; }
        float mrow[4] = {-1e30f, -1e30f, -1e30f, -1e30f};
        float lrow[4] = {0.f, 0.f, 0.f, 0.f};

        // preload tile 0
        bf16x8 kr0 = *(const bf16x8*)(kbase);
        bf16x8 kr1 = *(const bf16x8*)(kbase + 8);
        bf16x8 vr0 = *(const bf16x8*)(vbase);
        bf16x8 vr1 = *(const bf16x8*)(vbase + 8);

        for (int jt = 0; jt <= qt; ++jt) {
            __syncthreads();             // prior LDS reads complete
            *(bf16x8*)&Ks[srow * 72 + sch * 16]     = kr0;
            *(bf16x8*)&Ks[srow * 72 + sch * 16 + 8] = kr1;
            *(bf16x8*)&Vs[srow * 72 + sch * 16]     = vr0;
            *(bf16x8*)&Vs[srow * 72 + sch * 16 + 8] = vr1;
            __syncthreads();

            // prefetch tile jt+1 (flies during compute below)
            if (jt < qt) {
                const size_t ko = (size_t)(jt + 1) * 64 * (NG * DK);
                const size_t vo = (size_t)(jt + 1) * 64;
                kr0 = *(const bf16x8*)(kbase + ko);
                kr1 = *(const bf16x8*)(kbase + ko + 8);
                vr0 = *(const bf16x8*)(vbase + vo);
                vr1 = *(const bf16x8*)(vbase + vo + 8);
            }

            // S = Q K^T
            f32x4 s[4];
#pragma unroll
            for (int kt = 0; kt < 4; ++kt) {
                const bf16x8 kb0 = *(const bf16x8*)&Ks[(kt * 16 + l15) * 72 + quad * 8];
                const bf16x8 kb1 = *(const bf16x8*)&Ks[(kt * 16 + l15) * 72 + 32 + quad * 8];
                f32x4 acc = {0.f, 0.f, 0.f, 0.f};
                acc = __builtin_amdgcn_mfma_f32_16x16x32_bf16(qa0, kb0, acc, 0, 0, 0);
                acc = __builtin_amdgcn_mfma_f32_16x16x32_bf16(qa1, kb1, acc, 0, 0, 0);
                s[kt] = acc;
            }

            // scale + causal mask (diagonal tile only)
            if (jt == qt) {
#pragma unroll
                for (int kt = 0; kt < 4; ++kt)
#pragma unroll
                    for (int r = 0; r < 4; ++r) {
                        const int key = kt * 16 + l15;
                        const int row = wave * 16 + quad * 4 + r;
                        s[kt][r] = (key <= row) ? s[kt][r] * 0.125f : -1e30f;
                    }
            } else {
#pragma unroll
                for (int kt = 0; kt < 4; ++kt)
#pragma unroll
                    for (int r = 0; r < 4; ++r) s[kt][r] *= 0.125f;
            }

            // online softmax (row = quad*4 + r)
            float rmax[4];
#pragma unroll
            for (int r = 0; r < 4; ++r)
                rmax[r] = fmaxf(fmaxf(s[0][r], s[1][r]), fmaxf(s[2][r], s[3][r]));
#pragma unroll
            for (int off = 1; off <= 8; off <<= 1)
#pragma unroll
                for (int r = 0; r < 4; ++r)
                    rmax[r] = fmaxf(rmax[r], __shfl_xor(rmax[r], off, 64));

            float alpha[4];
#pragma unroll
            for (int r = 0; r < 4; ++r) {
                const float mn = fmaxf(mrow[r], rmax[r]);
                alpha[r] = __expf(mrow[r] - mn);
                mrow[r] = mn;
            }

            float p[4][4], rsum[4];
#pragma unroll
            for (int kt = 0; kt < 4; ++kt)
#pragma unroll
                for (int r = 0; r < 4; ++r)
                    p[kt][r] = __expf(s[kt][r] - mrow[r]);
#pragma unroll
            for (int r = 0; r < 4; ++r)
                rsum[r] = (p[0][r] + p[1][r]) + (p[2][r] + p[3][r]);
#pragma unroll
            for (int off = 1; off <= 8; off <<= 1)
#pragma unroll
                for (int r = 0; r < 4; ++r)
                    rsum[r] += __shfl_xor(rsum[r], off, 64);
#pragma unroll
            for (int r = 0; r < 4; ++r)
                lrow[r] = lrow[r] * alpha[r] + rsum[r];
#pragma unroll
            for (int dt = 0; dt < 4; ++dt)
#pragma unroll
                for (int r = 0; r < 4; ++r)
                    o[dt][r] *= alpha[r];

            // P: C-layout -> A-layout via per-wave LDS region
            ushort* Pw = &Ps[wave][0];
#pragma unroll
            for (int kt = 0; kt < 4; ++kt)
#pragma unroll
                for (int r = 0; r < 4; ++r)
                    Pw[(quad * 4 + r) * 72 + kt * 16 + l15] = f32_to_bf16(p[kt][r]);
            const bf16x8 pa0 = *(const bf16x8*)&Pw[l15 * 72 + quad * 8];
            const bf16x8 pa1 = *(const bf16x8*)&Pw[l15 * 72 + 32 + quad * 8];

            // O += P V
#pragma unroll
            for (int dt = 0; dt < 4; ++dt) {
                const bf16x8 vb0 = *(const bf16x8*)&Vs[(dt * 16 + l15) * 72 + quad * 8];
                const bf16x8 vb1 = *(const bf16x8*)&Vs[(dt * 16 + l15) * 72 + 32 + quad * 8];
                o[dt] = __builtin_amdgcn_mfma_f32_16x16x32_bf16(pa0, vb0, o[dt], 0, 0, 0);
                o[dt] = __builtin_amdgcn_mfma_f32_16x16x32_bf16(pa1, vb1, o[dt], 0, 0, 0);
            }
        }

        float inv[4];
#pragma unroll
        for (int r = 0; r < 4; ++r) inv[r] = 1.0f / lrow[r];
#pragma unroll
        for (int dt = 0; dt < 4; ++dt)
#pragma unroll
            for (int r = 0; r < 4; ++r)
                Ab[(size_t)(qr + quad * 4 + r) * (NH * DV) + (size_t)h * DV + dt * 16 + l15] =
                    f32_to_bf16(o[dt][r] * inv[r]);
    }
}

// ---------------------------------------------------------------------------
extern "C" void kernel_launch(void* const* d_in, const int* in_sizes, int n_in,
                              void* d_out, int out_size, void* d_ws, size_t ws_size,
                              hipStream_t stream) {
    const float* queries = (const float*)d_in[0];
    const float* keys    = (const float*)d_in[1];
    const float* values  = (const float*)d_in[2];
    const float* Wq      = (const float*)d_in[3];
    const float* bq      = (const float*)d_in[4];
    const float* Wk      = (const float*)d_in[5];
    const float* bk      = (const float*)d_in[6];
    const float* Wv      = (const float*)d_in[7];
    const float* bv      = (const float*)d_in[8];
    const float* Wo      = (const float*)d_in[9];
    const float* bo      = (const float*)d_in[10];
    float* out = (float*)d_out;

    const size_t MB = 1024 * 1024;
    unsigned char* w = (unsigned char*)d_ws;
    ushort* Xq  = (ushort*)(w + 0 * MB);    // [2048][2048] bf16
    ushort* Xk  = (ushort*)(w + 8 * MB);
    ushort* Xv  = (ushort*)(w + 16 * MB);
    ushort* Wqt = (ushort*)(w + 24 * MB);   // [2048][2048]
    ushort* Wkt = (ushort*)(w + 32 * MB);   // [512][2048]
    ushort* Wvt = (ushort*)(w + 34 * MB);
    ushort* Wot = (ushort*)(w + 36 * MB);   // [2048][2048]
    ushort* Qb  = (ushort*)(w + 44 * MB);   // [2048][2048]
    ushort* Kb  = (ushort*)(w + 52 * MB);   // [2048][512]
    ushort* Vb  = (ushort*)(w + 54 * MB);
    ushort* Ab  = (ushort*)(w + 56 * MB);   // [2048][2048]
    // V^T [512][2048] reuses the Xk region (dead after the K projection)
    ushort* Vtp = (ushort*)(w + 8 * MB);

    const int n8 = (S_LEN * DMODEL) / 8;
    cast_f32_to_bf16<<<1024, 256, 0, stream>>>(queries, Xq, n8);
    cast_f32_to_bf16<<<1024, 256, 0, stream>>>(keys,    Xk, n8);
    cast_f32_to_bf16<<<1024, 256, 0, stream>>>(values,  Xv, n8);

    dim3 tb(32, 8);
    transpose_cast_bf16<<<dim3(2048 / 32, 2048 / 32), tb, 0, stream>>>(Wq, Wqt, DMODEL, 2048);
    transpose_cast_bf16<<<dim3(512 / 32,  2048 / 32), tb, 0, stream>>>(Wk, Wkt, DMODEL, 512);
    transpose_cast_bf16<<<dim3(512 / 32,  2048 / 32), tb, 0, stream>>>(Wv, Wvt, DMODEL, 512);
    transpose_cast_bf16<<<dim3(2048 / 32, 2048 / 32), tb, 0, stream>>>(Wo, Wot, DMODEL, 2048);

    // Q projection: [2048,2048] @ [2048,2048]
    gemm_bf16_v2<false><<<dim3(2048 / 64, 2048 / 128), 256, 0, stream>>>(
        Xq, Wqt, bq, Qb, 2048, DMODEL);
    // K and V projections fused (z=0: K, z=1: V)
    gemm_kv<<<dim3(512 / 64, 2048 / 128, 2), 256, 0, stream>>>(
        Xk, Xv, Wkt, Wvt, bk, bv, Kb, Vb, 512, DMODEL);

    // V [2048][512] -> V^T [512][2048]
    transpose_bf16<<<dim3(512 / 32, 2048 / 32), tb, 0, stream>>>(Vb, Vtp, S_LEN, 512);

    // attention: paired q-tiles for perfect causal balance
    gqa_attn_mfma<<<dim3(16, 32), 256, 0, stream>>>(Qb, Kb, Vtp, Ab);

    // O projection: [2048,2048] @ [2048,2048] -> f32 out
    gemm_bf16_v2<true><<<dim3(2048 / 64, 2048 / 128), 256, 0, stream>>>(
        Ab, Wot, bo, out, 2048, DMODEL);
}